// Round 17
// baseline (174.784 us; speedup 1.0000x reference)
//
#include <hip/hip_runtime.h>

typedef unsigned short u16;
typedef unsigned int   u32;
typedef __attribute__((ext_vector_type(8))) short bf16x8;   // 8 bf16 = 4 VGPRs
typedef __attribute__((ext_vector_type(4))) short bf16x4;   // 4 bf16 = 2 VGPRs
typedef __attribute__((ext_vector_type(4))) float f32x4;    // MFMA 16x16 accumulator
typedef __attribute__((ext_vector_type(2))) u32 u32x2;

union F8 { bf16x8 v; u32 u[4]; };
union F4 { bf16x4 v; u32 u[2]; };

__device__ __forceinline__ u16 f2b(float f) {
    unsigned u = __builtin_bit_cast(unsigned, f);
    return (u16)((u + 0x7FFFu + ((u >> 16) & 1u)) >> 16);   // RNE fp32->bf16
}
// RNE pack via rounding-add + v_perm_b32 (bit-identical to f2b pair; R15-
// validated). (gfx950 lessons: asm v_cvt_pk_bf16_f32 truncates -> 2.25e-2
// error; _1k MFMA builtins NaN. Use neither.)
__device__ __forceinline__ u32 rneu(u32 u) { return u + 0x7FFFu + ((u >> 16) & 1u); }
__device__ __forceinline__ u32 pkbf(float a, float b) {
#if __has_builtin(__builtin_amdgcn_perm)
    u32 ua = rneu(__builtin_bit_cast(u32, a));
    u32 ub = rneu(__builtin_bit_cast(u32, b));
    return __builtin_amdgcn_perm(ub, ua, 0x07060302u);  // {ub.hi16, ua.hi16}
#else
    return ((u32)f2b(b) << 16) | (u32)f2b(a);
#endif
}

// K=16 MFMA via the proven K=32 instruction: data in k-slots 0-3, zeros in
// 4-7, identically on both operands -> exact.
__device__ __forceinline__ f32x4 mfma16(F4 a, F4 b, f32x4 c) {
    F8 a8, b8;
    a8.u[0] = a.u[0]; a8.u[1] = a.u[1]; a8.u[2] = 0; a8.u[3] = 0;
    b8.u[0] = b.u[0]; b8.u[1] = b.u[1]; b8.u[2] = 0; b8.u[3] = 0;
    return __builtin_amdgcn_mfma_f32_16x16x32_bf16(a8.v, b8.v, c, 0, 0, 0);
}

// Stage this wave's 1KB slice of tile-PAIR p (8KB = tiles 2p,2p+1) into the
// 3-pair LDS ring. 8 waves x 64 lanes x 16B = 8KB. One instr/wave/pair.
__device__ __forceinline__ void stage_pair(const u16* wfrag, u16* ldsbase,
                                           int p, int wave, int lane) {
    const char* gp = (const char*)wfrag + (((p * 8 + wave) << 10) | (lane << 4));
    char* lp = (char*)ldsbase + (((p % 3) << 13) | (wave << 10));
    __builtin_amdgcn_global_load_lds(
        (const __attribute__((address_space(1))) void*)gp,
        (__attribute__((address_space(3))) void*)lp, 16, 0, 0);
}

// Counted-vmcnt pipeline wait + raw barrier. vmcnt decrements IN ORDER, so
// proj-phase counts include younger stores. Never __syncthreads here.
#define PIPE_WAIT(N) { asm volatile("s_waitcnt vmcnt(" #N ")" ::: "memory"); \
    __builtin_amdgcn_sched_barrier(0); __builtin_amdgcn_s_barrier(); }

// ---------------------------------------------------------------------------
// Prep: 32-tile fragment STREAM (tile = 4KB), consumption order:
//  tiles 0-15: per head h: Q(2h), Q(2h+1), K(8+2h), K(9+2h)  (Q pre-scaled)
//  tiles 16-23: V (qkv nt = tile index), K=32 B-frags
//  tiles 24-31: proj nt 0-7, K=16 u32 frags (c=0..7 per tile)
//  float 32768..33791: bias dense [h][query][key]; 33792..34175: qkv_b scaled.
// ---------------------------------------------------------------------------
__global__ void prep_kernel(const float* __restrict__ qkv_w,
                            const float* __restrict__ proj_w,
                            const float* __restrict__ bias_tbl,
                            const float* __restrict__ qkv_b,
                            u16* __restrict__ wsb, float* __restrict__ wsf)
{
    const float scale = 0.17677669529663689f;   // 32^-0.5
    int tid = blockIdx.x * 256 + threadIdx.x;
    if (tid < 49152) {                      // qkv stream tiles 0..23
        int i = tid & 7, l = (tid >> 3) & 63, w = (tid >> 9) & 3, t = tid >> 11;
        int nt;
        if (t < 16) { int h = t >> 2, r = t & 3;
                      nt = (r < 2) ? (2 * h + r) : (8 + 2 * h + (r - 2)); }
        else nt = t;                        // V tiles: nt = 16..23
        int k = w * 32 + (l >> 4) * 8 + i;
        int col = nt * 16 + (l & 15);
        float wv = qkv_w[k * 384 + col];
        if (col < 128) wv *= scale;         // fold softmax scale into Q
        wsb[tid] = f2b(wv);
    } else if (tid < 57344) {               // proj stream tiles 24..31
        int e = tid - 49152;
        int nt = e >> 10, rem = e & 1023;
        int c = rem >> 7, le = rem & 127, l = le >> 1, j = le & 1;
        int col = nt * 16 + (l & 15);
        int d = c * 16 + 4 * (l >> 4) + 2 * j;
        u32 val = ((u32)f2b(proj_w[(d + 1) * 128 + col]) << 16)
                |  (u32)f2b(proj_w[d * 128 + col]);
        ((u32*)wsb)[(24 + nt) * 1024 + c * 128 + l * 2 + j] = val;
    } else if (tid < 58368) {               // bias expand [h][query][key]
        int e = tid - 57344;
        int h = e >> 8, t1 = (e >> 4) & 15, t2 = e & 15;
        int idx = ((t1 >> 2) - (t2 >> 2) + 3) * 7 + ((t1 & 3) - (t2 & 3) + 3);
        wsf[32768 + e] = bias_tbl[idx * 4 + h];
    } else if (tid < 58752) {               // qkv_b, Q part pre-scaled
        int e = tid - 58368;
        wsf[33792 + e] = qkv_b[e] * (e < 128 ? scale : 1.0f);
    }
}

// ---------------------------------------------------------------------------
// Fused window attention: EIGHT waves/block (512 thr), TWO windows/wave ->
// 16 windows share one 32-tile weight stream. 16 barrier-phases (1 tile-PAIR
// per phase), 3-pair ring (24KB), steady-state vmcnt(1), 1 DMA instr/wave/
// phase. Full occupancy needs only 4 blocks/CU. Math identical to R16:
// transposed qkv D-frags as direct K=16/K=32 MFMA operands, normal-orientation
// V (D-frag == PV A-op), ones-MFMA softmax denominator, K=16-frag proj.
// ---------------------------------------------------------------------------
__global__ __launch_bounds__(512, 6) void winattn_kernel(
    const float* __restrict__ x, const u16* __restrict__ wfrag,
    const float* __restrict__ proj_b, float* __restrict__ out)
{
    __shared__ alignas(16) u16 lds[15360];
    u16* ring = lds;                               // [0, 12288): 3 x 8KB pairs
    float* qkvbL  = (float*)(lds + 12288);         // 384 f
    float* biasL  = (float*)(lds + 13056);         // 1024 f
    float* projbL = (float*)(lds + 15104);         // 128 f

    const int tid  = threadIdx.x;
    const int wave = tid >> 6, lane = tid & 63;
    const int g = lane >> 4, q16 = lane & 15;

    const float* wsf = (const float*)wfrag;
    for (int e = tid; e < 384;  e += 512) qkvbL[e] = wsf[33792 + e];
    for (int e = tid; e < 1024; e += 512) biasL[e] = wsf[32768 + e];
    if (tid < 128) projbL[tid] = proj_b[tid];

    const int wpair = blockIdx.x * 8 + wave;
    const int wid0  = wpair * 2;                   // window A; B = wid0+1
    const int b = wid0 >> 10, rem = wid0 & 1023, wi = rem >> 5, wj = rem & 31;
    const int nTok = (wi * 4 + (q16 >> 2)) * 128 + wj * 4 + (q16 & 3);
    const float* xrowA = x + ((long)b * 16384 + nTok) * 128;
    const float* xrowB = xrowA + 512;

    // x fragments (per-lane bytes serve as BOTH A- and B-operand)
    F8 axA[4], axB[4];
    #pragma unroll
    for (int ks = 0; ks < 4; ++ks) {
        const float4* pA = (const float4*)(xrowA + ks * 32 + g * 8);
        float4 a0 = pA[0], a1 = pA[1];
        axA[ks].u[0] = pkbf(a0.x, a0.y); axA[ks].u[1] = pkbf(a0.z, a0.w);
        axA[ks].u[2] = pkbf(a1.x, a1.y); axA[ks].u[3] = pkbf(a1.z, a1.w);
        const float4* pB = (const float4*)(xrowB + ks * 32 + g * 8);
        float4 b0 = pB[0], b1 = pB[1];
        axB[ks].u[0] = pkbf(b0.x, b0.y); axB[ks].u[1] = pkbf(b0.z, b0.w);
        axB[ks].u[2] = pkbf(b1.x, b1.y); axB[ks].u[3] = pkbf(b1.z, b1.w);
    }
    __builtin_amdgcn_sched_barrier(0);  // pin x-loads before the drain
    __syncthreads();                    // tables visible; vmcnt drained to 0

    stage_pair(wfrag, lds, 0, wave, lane);
    stage_pair(wfrag, lds, 1, wave, lane);

    f32x4 z4 = {0.f, 0.f, 0.f, 0.f};
    F4 ones; ones.u[0] = 0x3f803f80u; ones.u[1] = 0x3f803f80u;
    F4 pPA[4], pPB[4];
    float rsA4[4], rsB4[4];
    u32 OpkA[8][2], OpkB[8][2];

    // Consume tile S (0/1) of pair P, TRANSPOSED orientation (8 MFMAs).
    #define QKV_TILE(P, S, NT, P0A, P1A, P0B, P1B) {                           \
        const u16* slot = ring + ((P) % 3) * 4096 + (S) * 2048;                \
        float4 bb = *(const float4*)&qkvbL[(NT) * 16 + 4 * g];                 \
        f32x4 accA = {bb.x, bb.y, bb.z, bb.w}, accB = accA;                    \
        _Pragma("unroll")                                                      \
        for (int ks = 0; ks < 4; ++ks) {                                       \
            bf16x8 frag = *(const bf16x8*)(slot + ks * 512 + lane * 8);        \
            accA = __builtin_amdgcn_mfma_f32_16x16x32_bf16(frag, axA[ks].v, accA, 0, 0, 0); \
            accB = __builtin_amdgcn_mfma_f32_16x16x32_bf16(frag, axB[ks].v, accB, 0, 0, 0); \
        }                                                                      \
        P0A = pkbf(accA[0], accA[1]); P1A = pkbf(accA[2], accA[3]);            \
        P0B = pkbf(accB[0], accB[1]); P1B = pkbf(accB[2], accB[3]);            \
    }

    // ---- QK phases 0..7 (pairs 0..7 = tiles 0..15) + per-head attention ----
    #pragma unroll
    for (int h = 0; h < 4; ++h) {
        u32 QA[2][2], QB[2][2], KA[2][2], KB[2][2];
        // phase 2h: Q pair (tiles 4h, 4h+1)
        PIPE_WAIT(1);
        QKV_TILE(2*h, 0, 2*h,     QA[0][0], QA[0][1], QB[0][0], QB[0][1]);
        QKV_TILE(2*h, 1, 2*h + 1, QA[1][0], QA[1][1], QB[1][0], QB[1][1]);
        stage_pair(wfrag, lds, 2*h + 2, wave, lane);
        // phase 2h+1: K pair (tiles 4h+2, 4h+3)
        PIPE_WAIT(1);
        QKV_TILE(2*h + 1, 0, 8 + 2*h, KA[0][0], KA[0][1], KB[0][0], KB[0][1]);
        QKV_TILE(2*h + 1, 1, 9 + 2*h, KA[1][0], KA[1][1], KB[1][0], KB[1][1]);
        stage_pair(wfrag, lds, 2*h + 3, wave, lane);
        // QK^T: ONE full K=32 MFMA per window (slot map identical on A and B)
        F8 kfA, qfA, kfB, qfB;
        kfA.u[0]=KA[0][0]; kfA.u[1]=KA[0][1]; kfA.u[2]=KA[1][0]; kfA.u[3]=KA[1][1];
        qfA.u[0]=QA[0][0]; qfA.u[1]=QA[0][1]; qfA.u[2]=QA[1][0]; qfA.u[3]=QA[1][1];
        kfB.u[0]=KB[0][0]; kfB.u[1]=KB[0][1]; kfB.u[2]=KB[1][0]; kfB.u[3]=KB[1][1];
        qfB.u[0]=QB[0][0]; qfB.u[1]=QB[0][1]; qfB.u[2]=QB[1][0]; qfB.u[3]=QB[1][1];
        f32x4 sA = __builtin_amdgcn_mfma_f32_16x16x32_bf16(kfA.v, qfA.v, z4, 0, 0, 0);
        f32x4 sB = __builtin_amdgcn_mfma_f32_16x16x32_bf16(kfB.v, qfB.v, z4, 0, 0, 0);
        // softmax (no max-sub; scale pre-folded); denominator via ones-MFMA
        float4 bias4 = *(const float4*)&biasL[(h * 16 + q16) * 16 + 4 * g];
        float eA0 = __expf(sA[0] + bias4.x), eA1 = __expf(sA[1] + bias4.y);
        float eA2 = __expf(sA[2] + bias4.z), eA3 = __expf(sA[3] + bias4.w);
        float eB0 = __expf(sB[0] + bias4.x), eB1 = __expf(sB[1] + bias4.y);
        float eB2 = __expf(sB[2] + bias4.z), eB3 = __expf(sB[3] + bias4.w);
        pPA[h].u[0] = pkbf(eA0, eA1); pPA[h].u[1] = pkbf(eA2, eA3);
        pPB[h].u[0] = pkbf(eB0, eB1); pPB[h].u[1] = pkbf(eB2, eB3);
        f32x4 suA = mfma16(ones, pPA[h], z4);
        f32x4 suB = mfma16(ones, pPB[h], z4);
        rsA4[h] = 1.0f / suA[0];
        rsB4[h] = 1.0f / suB[0];
    }

    // ---- V phases 8..11 (pairs 8..11 = tiles 16..23), NORMAL orientation:
    //      D-frag [tok 4g+r][d q16] == PV A-operand. Head f per phase. ----
    #pragma unroll
    for (int f = 0; f < 4; ++f) {
        PIPE_WAIT(1);
        #pragma unroll
        for (int s = 0; s < 2; ++s) {
            int c = 2 * f + s;
            const u16* slot = ring + ((8 + f) % 3) * 4096 + s * 2048;
            float bvA = qkvbL[(16 + c) * 16 + q16];     // bias on col = d = q16
            f32x4 accA = {bvA, bvA, bvA, bvA}, accB = accA;
            #pragma unroll
            for (int ks = 0; ks < 4; ++ks) {
                bf16x8 frag = *(const bf16x8*)(slot + ks * 512 + lane * 8);
                accA = __builtin_amdgcn_mfma_f32_16x16x32_bf16(axA[ks].v, frag, accA, 0, 0, 0);
                accB = __builtin_amdgcn_mfma_f32_16x16x32_bf16(axB[ks].v, frag, accB, 0, 0, 0);
            }
            F4 vpA; vpA.u[0] = pkbf(accA[0], accA[1]); vpA.u[1] = pkbf(accA[2], accA[3]);
            F4 vpB; vpB.u[0] = pkbf(accB[0], accB[1]); vpB.u[1] = pkbf(accB[2], accB[3]);
            f32x4 oA = mfma16(vpA, pPA[f], z4);
            f32x4 oB = mfma16(vpB, pPB[f], z4);
            float ra = rsA4[f], rb = rsB4[f];
            OpkA[c][0] = pkbf(oA[0] * ra, oA[1] * ra);
            OpkA[c][1] = pkbf(oA[2] * ra, oA[3] * ra);
            OpkB[c][0] = pkbf(oB[0] * rb, oB[1] * rb);
            OpkB[c][1] = pkbf(oB[2] * rb, oB[3] * rb);
        }
        stage_pair(wfrag, lds, 10 + f, wave, lane);
    }

    // ---- proj phases 12..15 (pairs 12..15 = tiles 24..31), inline stores ---
    // FIFO vmcnt with 4 stores/phase: waits {1, 5, 5, 4} (set-size counts,
    // robust to store/stage ordering within a phase).
    const long obaseA = ((long)b * 16384 + nTok) * 128;
    const long obaseB = obaseA + 512;
    #pragma unroll
    for (int f = 0; f < 4; ++f) {
        if (f == 0)      PIPE_WAIT(1)
        else if (f == 3) PIPE_WAIT(4)
        else             PIPE_WAIT(5)
        #pragma unroll
        for (int s = 0; s < 2; ++s) {
            int nt = 2 * f + s;
            const u32* slot32 = (const u32*)(ring + ((12 + f) % 3) * 4096 + s * 2048);
            float4 pb = *(const float4*)&projbL[nt * 16 + 4 * g];
            f32x4 accA = {pb.x, pb.y, pb.z, pb.w}, accB = accA;
            #pragma unroll
            for (int cp = 0; cp < 4; ++cp) {
                int c = 2 * cp;
                u32x2 wa = *(const u32x2*)&slot32[c * 128 + lane * 2];
                u32x2 wb = *(const u32x2*)&slot32[(c + 1) * 128 + lane * 2];
                F8 wf; wf.u[0] = wa.x; wf.u[1] = wa.y; wf.u[2] = wb.x; wf.u[3] = wb.y;
                F8 bA; bA.u[0] = OpkA[c][0]; bA.u[1] = OpkA[c][1];
                       bA.u[2] = OpkA[c+1][0]; bA.u[3] = OpkA[c+1][1];
                F8 bB; bB.u[0] = OpkB[c][0]; bB.u[1] = OpkB[c][1];
                       bB.u[2] = OpkB[c+1][0]; bB.u[3] = OpkB[c+1][1];
                accA = __builtin_amdgcn_mfma_f32_16x16x32_bf16(wf.v, bA.v, accA, 0, 0, 0);
                accB = __builtin_amdgcn_mfma_f32_16x16x32_bf16(wf.v, bB.v, accB, 0, 0, 0);
            }
            float4 oA; oA.x = accA[0]; oA.y = accA[1]; oA.z = accA[2]; oA.w = accA[3];
            *(float4*)&out[obaseA + nt * 16 + 4 * g] = oA;
            float4 oB; oB.x = accB[0]; oB.y = accB[1]; oB.z = accB[2]; oB.w = accB[3];
            *(float4*)&out[obaseB + nt * 16 + 4 * g] = oB;
        }
        if (f < 2) stage_pair(wfrag, lds, 14 + f, wave, lane);
    }
}

extern "C" void kernel_launch(void* const* d_in, const int* in_sizes, int n_in,
                              void* d_out, int out_size, void* d_ws, size_t ws_size,
                              hipStream_t stream)
{
    const float* x        = (const float*)d_in[0];
    const float* qkv_w    = (const float*)d_in[3];
    const float* qkv_b    = (const float*)d_in[4];
    const float* proj_w   = (const float*)d_in[5];
    const float* proj_b   = (const float*)d_in[6];
    const float* bias_tbl = (const float*)d_in[7];

    u16*   wsb = (u16*)d_ws;
    float* wsf = (float*)d_ws;

    prep_kernel<<<230, 256, 0, stream>>>(qkv_w, proj_w, bias_tbl, qkv_b, wsb, wsf);
    winattn_kernel<<<1024, 512, 0, stream>>>(x, wsb, proj_b, (float*)d_out);
}

// Round 18
// 74.833 us; speedup vs baseline: 2.3356x; 2.3356x over previous
//
#include <hip/hip_runtime.h>

typedef unsigned short u16;
typedef unsigned int   u32;
typedef __attribute__((ext_vector_type(8))) short bf16x8;   // 8 bf16 = 4 VGPRs
typedef __attribute__((ext_vector_type(4))) short bf16x4;   // 4 bf16 = 2 VGPRs
typedef __attribute__((ext_vector_type(4))) float f32x4;    // MFMA 16x16 accumulator
typedef __attribute__((ext_vector_type(2))) u32 u32x2;

union F8 { bf16x8 v; u32 u[4]; };
union F4 { bf16x4 v; u32 u[2]; };

__device__ __forceinline__ u16 f2b(float f) {
    unsigned u = __builtin_bit_cast(unsigned, f);
    return (u16)((u + 0x7FFFu + ((u >> 16) & 1u)) >> 16);   // RNE fp32->bf16
}
// RNE pack via rounding-add + v_perm_b32 (bit-identical to f2b pair; R15-
// validated). (gfx950 lessons: asm v_cvt_pk_bf16_f32 truncates -> 2.25e-2
// error; _1k MFMA builtins NaN; tight launch_bounds min-waves -> spill
// catastrophe (R17: VGPR 60->40, FETCH +163MB, 2.4x slower). Avoid all.)
__device__ __forceinline__ u32 rneu(u32 u) { return u + 0x7FFFu + ((u >> 16) & 1u); }
__device__ __forceinline__ u32 pkbf(float a, float b) {
#if __has_builtin(__builtin_amdgcn_perm)
    u32 ua = rneu(__builtin_bit_cast(u32, a));
    u32 ub = rneu(__builtin_bit_cast(u32, b));
    return __builtin_amdgcn_perm(ub, ua, 0x07060302u);  // {ub.hi16, ua.hi16}
#else
    return ((u32)f2b(b) << 16) | (u32)f2b(a);
#endif
}

// K=16 MFMA via the proven K=32 instruction: data in k-slots 0-3, zeros in
// 4-7, identically on both operands -> exact.
__device__ __forceinline__ f32x4 mfma16(F4 a, F4 b, f32x4 c) {
    F8 a8, b8;
    a8.u[0] = a.u[0]; a8.u[1] = a.u[1]; a8.u[2] = 0; a8.u[3] = 0;
    b8.u[0] = b.u[0]; b8.u[1] = b.u[1]; b8.u[2] = 0; b8.u[3] = 0;
    return __builtin_amdgcn_mfma_f32_16x16x32_bf16(a8.v, b8.v, c, 0, 0, 0);
}

// Stage one 1KB fragment (this wave's quarter of stream tile t) into the LDS
// ring, zero VGPR cost. Stream tile t at byte t*4096; ring slot = t%3.
__device__ __forceinline__ void stage_tile(const u16* wfrag, u16* ldsbase,
                                           int t, int wave, int lane) {
    const char* gp = (const char*)wfrag + (((t * 4 + wave) << 10) | (lane << 4));
    char* lp = (char*)ldsbase + (((t % 3) << 12) | (wave << 10));
    __builtin_amdgcn_global_load_lds(
        (const __attribute__((address_space(1))) void*)gp,
        (__attribute__((address_space(3))) void*)lp, 16, 0, 0);
}

// Counted-vmcnt pipeline wait + raw barrier. vmcnt decrements IN ORDER, so
// proj-phase counts include younger stores. Never __syncthreads here.
#define PIPE_WAIT(N) { asm volatile("s_waitcnt vmcnt(" #N ")" ::: "memory"); \
    __builtin_amdgcn_sched_barrier(0); __builtin_amdgcn_s_barrier(); }

// ---------------------------------------------------------------------------
// Prep: 32-tile fragment STREAM (tile = 4KB), consumption order:
//  tiles 0-15: per head h: Q(2h), Q(2h+1), K(8+2h), K(9+2h)  (Q pre-scaled)
//  tiles 16-23: V (qkv nt = tile index), K=32 B-frags
//  tiles 24-31: proj nt 0-7, K=16 u32 frags (c=0..7 per tile)
//  float 32768..33791: bias dense [h][query][key]; 33792..34175: qkv_b scaled.
// ---------------------------------------------------------------------------
__global__ void prep_kernel(const float* __restrict__ qkv_w,
                            const float* __restrict__ proj_w,
                            const float* __restrict__ bias_tbl,
                            const float* __restrict__ qkv_b,
                            u16* __restrict__ wsb, float* __restrict__ wsf)
{
    const float scale = 0.17677669529663689f;   // 32^-0.5
    int tid = blockIdx.x * 256 + threadIdx.x;
    if (tid < 49152) {                      // qkv stream tiles 0..23
        int i = tid & 7, l = (tid >> 3) & 63, w = (tid >> 9) & 3, t = tid >> 11;
        int nt;
        if (t < 16) { int h = t >> 2, r = t & 3;
                      nt = (r < 2) ? (2 * h + r) : (8 + 2 * h + (r - 2)); }
        else nt = t;                        // V tiles: nt = 16..23
        int k = w * 32 + (l >> 4) * 8 + i;
        int col = nt * 16 + (l & 15);
        float wv = qkv_w[k * 384 + col];
        if (col < 128) wv *= scale;         // fold softmax scale into Q
        wsb[tid] = f2b(wv);
    } else if (tid < 57344) {               // proj stream tiles 24..31
        int e = tid - 49152;
        int nt = e >> 10, rem = e & 1023;
        int c = rem >> 7, le = rem & 127, l = le >> 1, j = le & 1;
        int col = nt * 16 + (l & 15);
        int d = c * 16 + 4 * (l >> 4) + 2 * j;
        u32 val = ((u32)f2b(proj_w[(d + 1) * 128 + col]) << 16)
                |  (u32)f2b(proj_w[d * 128 + col]);
        ((u32*)wsb)[(24 + nt) * 1024 + c * 128 + l * 2 + j] = val;
    } else if (tid < 58368) {               // bias expand [h][query][key]
        int e = tid - 57344;
        int h = e >> 8, t1 = (e >> 4) & 15, t2 = e & 15;
        int idx = ((t1 >> 2) - (t2 >> 2) + 3) * 7 + ((t1 & 3) - (t2 & 3) + 3);
        wsf[32768 + e] = bias_tbl[idx * 4 + h];
    } else if (tid < 58752) {               // qkv_b, Q part pre-scaled
        int e = tid - 58368;
        wsf[33792 + e] = qkv_b[e] * (e < 128 ? scale : 1.0f);
    }
}

// ---------------------------------------------------------------------------
// Fused window attention (R16 structure = validated optimum + T5 setprio):
// 4 waves/block, TWO windows/wave. 3-slot ring, 1 tile/phase, vmcnt(1).
// Transposed qkv D-frags as direct K=16/K=32 MFMA operands; NORMAL-orientation
// V (D-frag == PV A-op, no LDS transpose); ones-MFMA softmax denominator;
// K=16-frag proj. s_setprio(1) wraps MFMA clusters so MFMA-phase waves win
// CU arbitration over other blocks' staging phases (T5; blocks are NOT
// lockstep across the CU).
// ---------------------------------------------------------------------------
__global__ __launch_bounds__(256, 4) void winattn_kernel(
    const float* __restrict__ x, const u16* __restrict__ wfrag,
    const float* __restrict__ proj_b, float* __restrict__ out)
{
    __shared__ alignas(16) u16 lds[9216];
    u16* ring = lds;                               // [0, 6144): 3 x 4KB slots
    float* qkvbL  = (float*)(lds + 6144);          // 384 f
    float* biasL  = (float*)(lds + 6912);          // 1024 f
    float* projbL = (float*)(lds + 8960);          // 128 f

    const int tid  = threadIdx.x;
    const int wave = tid >> 6, lane = tid & 63;
    const int g = lane >> 4, q16 = lane & 15;

    const float* wsf = (const float*)wfrag;
    for (int e = tid; e < 384;  e += 256) qkvbL[e] = wsf[33792 + e];
    for (int e = tid; e < 1024; e += 256) biasL[e] = wsf[32768 + e];
    if (tid < 128) projbL[tid] = proj_b[tid];

    const int wpair = blockIdx.x * 4 + wave;
    const int wid0  = wpair * 2;                   // window A; B = wid0+1
    const int b = wid0 >> 10, rem = wid0 & 1023, wi = rem >> 5, wj = rem & 31;
    const int nTok = (wi * 4 + (q16 >> 2)) * 128 + wj * 4 + (q16 & 3);
    const float* xrowA = x + ((long)b * 16384 + nTok) * 128;
    const float* xrowB = xrowA + 512;

    // x fragments (per-lane bytes serve as BOTH A- and B-operand)
    F8 axA[4], axB[4];
    #pragma unroll
    for (int ks = 0; ks < 4; ++ks) {
        const float4* pA = (const float4*)(xrowA + ks * 32 + g * 8);
        float4 a0 = pA[0], a1 = pA[1];
        axA[ks].u[0] = pkbf(a0.x, a0.y); axA[ks].u[1] = pkbf(a0.z, a0.w);
        axA[ks].u[2] = pkbf(a1.x, a1.y); axA[ks].u[3] = pkbf(a1.z, a1.w);
        const float4* pB = (const float4*)(xrowB + ks * 32 + g * 8);
        float4 b0 = pB[0], b1 = pB[1];
        axB[ks].u[0] = pkbf(b0.x, b0.y); axB[ks].u[1] = pkbf(b0.z, b0.w);
        axB[ks].u[2] = pkbf(b1.x, b1.y); axB[ks].u[3] = pkbf(b1.z, b1.w);
    }
    __builtin_amdgcn_sched_barrier(0);  // pin x-loads before the drain
    __syncthreads();                    // tables visible; vmcnt drained to 0

    stage_tile(wfrag, lds, 0, wave, lane);
    stage_tile(wfrag, lds, 1, wave, lane);

    f32x4 z4 = {0.f, 0.f, 0.f, 0.f};
    F4 ones; ones.u[0] = 0x3f803f80u; ones.u[1] = 0x3f803f80u;
    F4 pPA[4], pPB[4];
    float rsA4[4], rsB4[4];
    u32 OpkA[8][2], OpkB[8][2];

    // Consume one qkv tile TRANSPOSED (8 MFMAs), return packed D-frags.
    // setprio(1) around the MFMA cluster (T5).
    #define QKV_TILE(T, NT, P0A, P1A, P0B, P1B) {                              \
        const u16* slot = ring + ((T) % 3) * 2048;                             \
        float4 bb = *(const float4*)&qkvbL[(NT) * 16 + 4 * g];                 \
        f32x4 accA = {bb.x, bb.y, bb.z, bb.w}, accB = accA;                    \
        __builtin_amdgcn_s_setprio(1);                                         \
        _Pragma("unroll")                                                      \
        for (int ks = 0; ks < 4; ++ks) {                                       \
            bf16x8 frag = *(const bf16x8*)(slot + ks * 512 + lane * 8);        \
            accA = __builtin_amdgcn_mfma_f32_16x16x32_bf16(frag, axA[ks].v, accA, 0, 0, 0); \
            accB = __builtin_amdgcn_mfma_f32_16x16x32_bf16(frag, axB[ks].v, accB, 0, 0, 0); \
        }                                                                      \
        __builtin_amdgcn_s_setprio(0);                                         \
        P0A = pkbf(accA[0], accA[1]); P1A = pkbf(accA[2], accA[3]);            \
        P0B = pkbf(accB[0], accB[1]); P1B = pkbf(accB[2], accB[3]);            \
    }

    // ---- per-head Q,K tiles (stream 0..15) + attention ----
    #pragma unroll
    for (int h = 0; h < 4; ++h) {
        u32 QA[2][2], QB[2][2], KA[2][2], KB[2][2];
        #pragma unroll
        for (int r = 0; r < 4; ++r) {
            int t = 4 * h + r;
            PIPE_WAIT(1);
            int nt = (r < 2) ? (2 * h + r) : (8 + 2 * h + (r - 2));
            if (r == 0)      QKV_TILE(t, nt, QA[0][0], QA[0][1], QB[0][0], QB[0][1])
            else if (r == 1) QKV_TILE(t, nt, QA[1][0], QA[1][1], QB[1][0], QB[1][1])
            else if (r == 2) QKV_TILE(t, nt, KA[0][0], KA[0][1], KB[0][0], KB[0][1])
            else             QKV_TILE(t, nt, KA[1][0], KA[1][1], KB[1][0], KB[1][1])
            stage_tile(wfrag, lds, t + 2, wave, lane);
        }
        // QK^T: ONE full K=32 MFMA per window (slot map identical on A and B)
        F8 kfA, qfA, kfB, qfB;
        kfA.u[0]=KA[0][0]; kfA.u[1]=KA[0][1]; kfA.u[2]=KA[1][0]; kfA.u[3]=KA[1][1];
        qfA.u[0]=QA[0][0]; qfA.u[1]=QA[0][1]; qfA.u[2]=QA[1][0]; qfA.u[3]=QA[1][1];
        kfB.u[0]=KB[0][0]; kfB.u[1]=KB[0][1]; kfB.u[2]=KB[1][0]; kfB.u[3]=KB[1][1];
        qfB.u[0]=QB[0][0]; qfB.u[1]=QB[0][1]; qfB.u[2]=QB[1][0]; qfB.u[3]=QB[1][1];
        __builtin_amdgcn_s_setprio(1);
        f32x4 sA = __builtin_amdgcn_mfma_f32_16x16x32_bf16(kfA.v, qfA.v, z4, 0, 0, 0);
        f32x4 sB = __builtin_amdgcn_mfma_f32_16x16x32_bf16(kfB.v, qfB.v, z4, 0, 0, 0);
        __builtin_amdgcn_s_setprio(0);
        // softmax (no max-sub; scale pre-folded); denominator via ones-MFMA
        float4 bias4 = *(const float4*)&biasL[(h * 16 + q16) * 16 + 4 * g];
        float eA0 = __expf(sA[0] + bias4.x), eA1 = __expf(sA[1] + bias4.y);
        float eA2 = __expf(sA[2] + bias4.z), eA3 = __expf(sA[3] + bias4.w);
        float eB0 = __expf(sB[0] + bias4.x), eB1 = __expf(sB[1] + bias4.y);
        float eB2 = __expf(sB[2] + bias4.z), eB3 = __expf(sB[3] + bias4.w);
        pPA[h].u[0] = pkbf(eA0, eA1); pPA[h].u[1] = pkbf(eA2, eA3);
        pPB[h].u[0] = pkbf(eB0, eB1); pPB[h].u[1] = pkbf(eB2, eB3);
        f32x4 suA = mfma16(ones, pPA[h], z4);
        f32x4 suB = mfma16(ones, pPB[h], z4);
        rsA4[h] = 1.0f / suA[0];
        rsB4[h] = 1.0f / suB[0];
    }

    // ---- V tiles (stream 16..23), NORMAL orientation: D-frag == PV A-op ----
    #pragma unroll
    for (int c = 0; c < 8; ++c) {
        int t = 16 + c;
        PIPE_WAIT(1);
        const u16* slot = ring + (t % 3) * 2048;
        float bvA = qkvbL[(16 + c) * 16 + q16];     // bias on col = d = q16
        f32x4 accA = {bvA, bvA, bvA, bvA}, accB = accA;
        __builtin_amdgcn_s_setprio(1);
        #pragma unroll
        for (int ks = 0; ks < 4; ++ks) {
            bf16x8 frag = *(const bf16x8*)(slot + ks * 512 + lane * 8);
            // normal orientation: A = x-frag, B = weight-frag
            accA = __builtin_amdgcn_mfma_f32_16x16x32_bf16(axA[ks].v, frag, accA, 0, 0, 0);
            accB = __builtin_amdgcn_mfma_f32_16x16x32_bf16(axB[ks].v, frag, accB, 0, 0, 0);
        }
        __builtin_amdgcn_s_setprio(0);
        // lane holds V[tok=4g+r][d=q16] -> pack along tok: PV A-operand.
        F4 vpA; vpA.u[0] = pkbf(accA[0], accA[1]); vpA.u[1] = pkbf(accA[2], accA[3]);
        F4 vpB; vpB.u[0] = pkbf(accB[0], accB[1]); vpB.u[1] = pkbf(accB[2], accB[3]);
        int hh = c >> 1;
        f32x4 oA = mfma16(vpA, pPA[hh], z4);
        f32x4 oB = mfma16(vpB, pPB[hh], z4);
        float ra = rsA4[hh], rb = rsB4[hh];
        OpkA[c][0] = pkbf(oA[0] * ra, oA[1] * ra);
        OpkA[c][1] = pkbf(oA[2] * ra, oA[3] * ra);
        OpkB[c][0] = pkbf(oB[0] * rb, oB[1] * rb);
        OpkB[c][1] = pkbf(oB[2] * rb, oB[3] * rb);
        stage_tile(wfrag, lds, t + 2, wave, lane);
    }

    // ---- proj tiles (24..31): chunk-pair full-K=32; in-pipeline stores ----
    // vmcnt is FIFO: counts below account for the 4 younger stores per phase.
    const long obaseA = ((long)b * 16384 + nTok) * 128;
    const long obaseB = obaseA + 512;
    #pragma unroll
    for (int nt = 0; nt < 8; ++nt) {
        int t = 24 + nt;
        if (nt == 0)      PIPE_WAIT(1)
        else if (nt == 7) PIPE_WAIT(2)
        else              PIPE_WAIT(3)
        const u32* slot32 = (const u32*)(ring + (t % 3) * 2048);
        float4 pb = *(const float4*)&projbL[nt * 16 + 4 * g];
        f32x4 accA = {pb.x, pb.y, pb.z, pb.w}, accB = accA;
        __builtin_amdgcn_s_setprio(1);
        #pragma unroll
        for (int cp = 0; cp < 4; ++cp) {
            int c = 2 * cp;
            u32x2 wa = *(const u32x2*)&slot32[c * 128 + lane * 2];
            u32x2 wb = *(const u32x2*)&slot32[(c + 1) * 128 + lane * 2];
            F8 wf; wf.u[0] = wa.x; wf.u[1] = wa.y; wf.u[2] = wb.x; wf.u[3] = wb.y;
            F8 bA; bA.u[0] = OpkA[c][0]; bA.u[1] = OpkA[c][1];
                   bA.u[2] = OpkA[c+1][0]; bA.u[3] = OpkA[c+1][1];
            F8 bB; bB.u[0] = OpkB[c][0]; bB.u[1] = OpkB[c][1];
                   bB.u[2] = OpkB[c+1][0]; bB.u[3] = OpkB[c+1][1];
            accA = __builtin_amdgcn_mfma_f32_16x16x32_bf16(wf.v, bA.v, accA, 0, 0, 0);
            accB = __builtin_amdgcn_mfma_f32_16x16x32_bf16(wf.v, bB.v, accB, 0, 0, 0);
        }
        __builtin_amdgcn_s_setprio(0);
        float4 oA; oA.x = accA[0]; oA.y = accA[1]; oA.z = accA[2]; oA.w = accA[3];
        *(float4*)&out[obaseA + nt * 16 + 4 * g] = oA;
        float4 oB; oB.x = accB[0]; oB.y = accB[1]; oB.z = accB[2]; oB.w = accB[3];
        *(float4*)&out[obaseB + nt * 16 + 4 * g] = oB;
        if (nt < 6) stage_tile(wfrag, lds, t + 2, wave, lane);
    }
}

extern "C" void kernel_launch(void* const* d_in, const int* in_sizes, int n_in,
                              void* d_out, int out_size, void* d_ws, size_t ws_size,
                              hipStream_t stream)
{
    const float* x        = (const float*)d_in[0];
    const float* qkv_w    = (const float*)d_in[3];
    const float* qkv_b    = (const float*)d_in[4];
    const float* proj_w   = (const float*)d_in[5];
    const float* proj_b   = (const float*)d_in[6];
    const float* bias_tbl = (const float*)d_in[7];

    u16*   wsb = (u16*)d_ws;
    float* wsf = (float*)d_ws;

    prep_kernel<<<230, 256, 0, stream>>>(qkv_w, proj_w, bias_tbl, qkv_b, wsb, wsf);
    winattn_kernel<<<2048, 256, 0, stream>>>(x, wsb, proj_b, (float*)d_out);
}

// Round 20
// 72.539 us; speedup vs baseline: 2.4095x; 1.0316x over previous
//
#include <hip/hip_runtime.h>

typedef unsigned short u16;
typedef unsigned int   u32;
typedef __attribute__((ext_vector_type(8))) short bf16x8;   // 8 bf16 = 4 VGPRs
typedef __attribute__((ext_vector_type(4))) short bf16x4;   // 4 bf16 = 2 VGPRs
typedef __attribute__((ext_vector_type(4))) float f32x4;    // MFMA 16x16 accumulator
typedef __attribute__((ext_vector_type(2))) u32 u32x2;

union F8 { bf16x8 v; u32 u[4]; };
union F4 { bf16x4 v; u32 u[2]; };

__device__ __forceinline__ u16 f2b(float f) {
    unsigned u = __builtin_bit_cast(unsigned, f);
    return (u16)((u + 0x7FFFu + ((u >> 16) & 1u)) >> 16);   // RNE fp32->bf16
}
// RNE pack via rounding-add + v_perm_b32 (bit-identical to f2b pair; R15-
// validated). (gfx950 lessons: asm v_cvt_pk_bf16_f32 truncates -> 2.25e-2
// error; _1k MFMA builtins NaN; tight launch_bounds min-waves -> spill
// catastrophe (R17); setprio null (R18); UNPINNED s_barrier lets the
// scheduler hoist ds_reads above the cross-wave DMA rendezvous -> replay
// races (R19). Avoid all.)
__device__ __forceinline__ u32 rneu(u32 u) { return u + 0x7FFFu + ((u >> 16) & 1u); }
__device__ __forceinline__ u32 pkbf(float a, float b) {
#if __has_builtin(__builtin_amdgcn_perm)
    u32 ua = rneu(__builtin_bit_cast(u32, a));
    u32 ub = rneu(__builtin_bit_cast(u32, b));
    return __builtin_amdgcn_perm(ub, ua, 0x07060302u);  // {ub.hi16, ua.hi16}
#else
    return ((u32)f2b(b) << 16) | (u32)f2b(a);
#endif
}

// K=16 MFMA via the proven K=32 instruction: data in k-slots 0-3, zeros in
// 4-7, identically on both operands -> exact.
__device__ __forceinline__ f32x4 mfma16(F4 a, F4 b, f32x4 c) {
    F8 a8, b8;
    a8.u[0] = a.u[0]; a8.u[1] = a.u[1]; a8.u[2] = 0; a8.u[3] = 0;
    b8.u[0] = b.u[0]; b8.u[1] = b.u[1]; b8.u[2] = 0; b8.u[3] = 0;
    return __builtin_amdgcn_mfma_f32_16x16x32_bf16(a8.v, b8.v, c, 0, 0, 0);
}

// Stage one 1KB fragment (this wave's quarter of stream tile t) into the LDS
// ring, zero VGPR cost. Stream tile t at byte t*4096; ring slot = t%3.
__device__ __forceinline__ void stage_tile(const u16* wfrag, u16* ldsbase,
                                           int t, int wave, int lane) {
    const char* gp = (const char*)wfrag + (((t * 4 + wave) << 10) | (lane << 4));
    char* lp = (char*)ldsbase + (((t % 3) << 12) | (wave << 10));
    __builtin_amdgcn_global_load_lds(
        (const __attribute__((address_space(1))) void*)gp,
        (__attribute__((address_space(3))) void*)lp, 16, 0, 0);
}

// Counted-vmcnt pipeline wait + raw barrier, DOUBLE-pinned: waves read tiles
// staged partly by OTHER waves, so no ds_read may cross the s_barrier in
// either direction (LLVM's s_barrier intrinsic does not model memory —
// unpinned, the scheduler hoisted reads above it; R19 replay race).
#define PIPE_WAIT(N) { asm volatile("s_waitcnt vmcnt(" #N ")" ::: "memory"); \
    __builtin_amdgcn_sched_barrier(0); __builtin_amdgcn_s_barrier(); \
    __builtin_amdgcn_sched_barrier(0); }

// ---------------------------------------------------------------------------
// Prep: 32-tile fragment STREAM (tile = 4KB), consumption order:
//  tiles 0-15: per head h: Q(2h), Q(2h+1), K(8+2h), K(9+2h)
//              (Q pre-scaled by scale*log2e for exp2-softmax)
//  tiles 16-23: V (qkv nt = tile index), K=32 B-frags
//  tiles 24-31: proj nt 0-7, K=16 u32 frags (c=0..7 per tile)
//  float 32768..33791: bias dense [h][query][key] * log2e
//  float 33792..34175: qkv_b (Q part * scale*log2e).
// ---------------------------------------------------------------------------
__global__ void prep_kernel(const float* __restrict__ qkv_w,
                            const float* __restrict__ proj_w,
                            const float* __restrict__ bias_tbl,
                            const float* __restrict__ qkv_b,
                            u16* __restrict__ wsb, float* __restrict__ wsf)
{
    const float l2e    = 1.4426950408889634f;            // log2(e)
    const float scale2 = 0.17677669529663689f * l2e;     // 32^-0.5 * log2e
    int tid = blockIdx.x * 256 + threadIdx.x;
    if (tid < 49152) {                      // qkv stream tiles 0..23
        int i = tid & 7, l = (tid >> 3) & 63, w = (tid >> 9) & 3, t = tid >> 11;
        int nt;
        if (t < 16) { int h = t >> 2, r = t & 3;
                      nt = (r < 2) ? (2 * h + r) : (8 + 2 * h + (r - 2)); }
        else nt = t;                        // V tiles: nt = 16..23
        int k = w * 32 + (l >> 4) * 8 + i;
        int col = nt * 16 + (l & 15);
        float wv = qkv_w[k * 384 + col];
        if (col < 128) wv *= scale2;        // fold scale AND log2e into Q
        wsb[tid] = f2b(wv);
    } else if (tid < 57344) {               // proj stream tiles 24..31
        int e = tid - 49152;
        int nt = e >> 10, rem = e & 1023;
        int c = rem >> 7, le = rem & 127, l = le >> 1, j = le & 1;
        int col = nt * 16 + (l & 15);
        int d = c * 16 + 4 * (l >> 4) + 2 * j;
        u32 val = ((u32)f2b(proj_w[(d + 1) * 128 + col]) << 16)
                |  (u32)f2b(proj_w[d * 128 + col]);
        ((u32*)wsb)[(24 + nt) * 1024 + c * 128 + l * 2 + j] = val;
    } else if (tid < 58368) {               // bias expand [h][query][key]*log2e
        int e = tid - 57344;
        int h = e >> 8, t1 = (e >> 4) & 15, t2 = e & 15;
        int idx = ((t1 >> 2) - (t2 >> 2) + 3) * 7 + ((t1 & 3) - (t2 & 3) + 3);
        wsf[32768 + e] = bias_tbl[idx * 4 + h] * l2e;
    } else if (tid < 58752) {               // qkv_b, Q part pre-scaled
        int e = tid - 58368;
        wsf[33792 + e] = qkv_b[e] * (e < 128 ? scale2 : 1.0f);
    }
}

// ---------------------------------------------------------------------------
// Fused window attention (R16 structure = validated optimum of this family):
// 4 waves/block, TWO windows/wave. 3-slot ring, 1 tile/phase, vmcnt(1).
// Transposed qkv D-frags as direct K=16/K=32 MFMA operands; NORMAL-orientation
// V (D-frag == PV A-op, no LDS transpose); ones-MFMA softmax denominator
// (P = exp2 of pre-folded args, no max-sub); K=16-frag proj.
// ---------------------------------------------------------------------------
__global__ __launch_bounds__(256, 4) void winattn_kernel(
    const float* __restrict__ x, const u16* __restrict__ wfrag,
    const float* __restrict__ proj_b, float* __restrict__ out)
{
    __shared__ alignas(16) u16 lds[9216];
    u16* ring = lds;                               // [0, 6144): 3 x 4KB slots
    float* qkvbL  = (float*)(lds + 6144);          // 384 f
    float* biasL  = (float*)(lds + 6912);          // 1024 f
    float* projbL = (float*)(lds + 8960);          // 128 f

    const int tid  = threadIdx.x;
    const int wave = tid >> 6, lane = tid & 63;
    const int g = lane >> 4, q16 = lane & 15;

    const float* wsf = (const float*)wfrag;
    for (int e = tid; e < 384;  e += 256) qkvbL[e] = wsf[33792 + e];
    for (int e = tid; e < 1024; e += 256) biasL[e] = wsf[32768 + e];
    if (tid < 128) projbL[tid] = proj_b[tid];

    const int wpair = blockIdx.x * 4 + wave;
    const int wid0  = wpair * 2;                   // window A; B = wid0+1
    const int b = wid0 >> 10, rem = wid0 & 1023, wi = rem >> 5, wj = rem & 31;
    const int nTok = (wi * 4 + (q16 >> 2)) * 128 + wj * 4 + (q16 & 3);
    const float* xrowA = x + ((long)b * 16384 + nTok) * 128;
    const float* xrowB = xrowA + 512;

    // x fragments (per-lane bytes serve as BOTH A- and B-operand)
    F8 axA[4], axB[4];
    #pragma unroll
    for (int ks = 0; ks < 4; ++ks) {
        const float4* pA = (const float4*)(xrowA + ks * 32 + g * 8);
        float4 a0 = pA[0], a1 = pA[1];
        axA[ks].u[0] = pkbf(a0.x, a0.y); axA[ks].u[1] = pkbf(a0.z, a0.w);
        axA[ks].u[2] = pkbf(a1.x, a1.y); axA[ks].u[3] = pkbf(a1.z, a1.w);
        const float4* pB = (const float4*)(xrowB + ks * 32 + g * 8);
        float4 b0 = pB[0], b1 = pB[1];
        axB[ks].u[0] = pkbf(b0.x, b0.y); axB[ks].u[1] = pkbf(b0.z, b0.w);
        axB[ks].u[2] = pkbf(b1.x, b1.y); axB[ks].u[3] = pkbf(b1.z, b1.w);
    }
    __builtin_amdgcn_sched_barrier(0);  // pin x-loads before the drain
    __syncthreads();                    // tables visible; vmcnt drained to 0

    stage_tile(wfrag, lds, 0, wave, lane);
    stage_tile(wfrag, lds, 1, wave, lane);

    f32x4 z4 = {0.f, 0.f, 0.f, 0.f};
    F4 ones; ones.u[0] = 0x3f803f80u; ones.u[1] = 0x3f803f80u;
    F4 pPA[4], pPB[4];
    float rsA4[4], rsB4[4];
    u32 OpkA[8][2], OpkB[8][2];

    // Consume one qkv tile TRANSPOSED (8 MFMAs), return packed D-frags.
    #define QKV_TILE(T, NT, P0A, P1A, P0B, P1B) {                              \
        const u16* slot = ring + ((T) % 3) * 2048;                             \
        float4 bb = *(const float4*)&qkvbL[(NT) * 16 + 4 * g];                 \
        f32x4 accA = {bb.x, bb.y, bb.z, bb.w}, accB = accA;                    \
        _Pragma("unroll")                                                      \
        for (int ks = 0; ks < 4; ++ks) {                                       \
            bf16x8 frag = *(const bf16x8*)(slot + ks * 512 + lane * 8);        \
            accA = __builtin_amdgcn_mfma_f32_16x16x32_bf16(frag, axA[ks].v, accA, 0, 0, 0); \
            accB = __builtin_amdgcn_mfma_f32_16x16x32_bf16(frag, axB[ks].v, accB, 0, 0, 0); \
        }                                                                      \
        P0A = pkbf(accA[0], accA[1]); P1A = pkbf(accA[2], accA[3]);            \
        P0B = pkbf(accB[0], accB[1]); P1B = pkbf(accB[2], accB[3]);            \
    }

    // ---- per-head Q,K tiles (stream 0..15) + attention ----
    #pragma unroll
    for (int h = 0; h < 4; ++h) {
        u32 QA[2][2], QB[2][2], KA[2][2], KB[2][2];
        #pragma unroll
        for (int r = 0; r < 4; ++r) {
            int t = 4 * h + r;
            PIPE_WAIT(1);
            int nt = (r < 2) ? (2 * h + r) : (8 + 2 * h + (r - 2));
            if (r == 0)      QKV_TILE(t, nt, QA[0][0], QA[0][1], QB[0][0], QB[0][1])
            else if (r == 1) QKV_TILE(t, nt, QA[1][0], QA[1][1], QB[1][0], QB[1][1])
            else if (r == 2) QKV_TILE(t, nt, KA[0][0], KA[0][1], KB[0][0], KB[0][1])
            else             QKV_TILE(t, nt, KA[1][0], KA[1][1], KB[1][0], KB[1][1])
            stage_tile(wfrag, lds, t + 2, wave, lane);
        }
        // QK^T: ONE full K=32 MFMA per window (slot map identical on A and B)
        F8 kfA, qfA, kfB, qfB;
        kfA.u[0]=KA[0][0]; kfA.u[1]=KA[0][1]; kfA.u[2]=KA[1][0]; kfA.u[3]=KA[1][1];
        qfA.u[0]=QA[0][0]; qfA.u[1]=QA[0][1]; qfA.u[2]=QA[1][0]; qfA.u[3]=QA[1][1];
        kfB.u[0]=KB[0][0]; kfB.u[1]=KB[0][1]; kfB.u[2]=KB[1][0]; kfB.u[3]=KB[1][1];
        qfB.u[0]=QB[0][0]; qfB.u[1]=QB[0][1]; qfB.u[2]=QB[1][0]; qfB.u[3]=QB[1][1];
        f32x4 sA = __builtin_amdgcn_mfma_f32_16x16x32_bf16(kfA.v, qfA.v, z4, 0, 0, 0);
        f32x4 sB = __builtin_amdgcn_mfma_f32_16x16x32_bf16(kfB.v, qfB.v, z4, 0, 0, 0);
        // softmax: P = exp2(S + bias')  (scale & log2e pre-folded; no max-sub)
        float4 bias4 = *(const float4*)&biasL[(h * 16 + q16) * 16 + 4 * g];
        float eA0 = exp2f(sA[0] + bias4.x), eA1 = exp2f(sA[1] + bias4.y);
        float eA2 = exp2f(sA[2] + bias4.z), eA3 = exp2f(sA[3] + bias4.w);
        float eB0 = exp2f(sB[0] + bias4.x), eB1 = exp2f(sB[1] + bias4.y);
        float eB2 = exp2f(sB[2] + bias4.z), eB3 = exp2f(sB[3] + bias4.w);
        pPA[h].u[0] = pkbf(eA0, eA1); pPA[h].u[1] = pkbf(eA2, eA3);
        pPB[h].u[0] = pkbf(eB0, eB1); pPB[h].u[1] = pkbf(eB2, eB3);
        f32x4 suA = mfma16(ones, pPA[h], z4);
        f32x4 suB = mfma16(ones, pPB[h], z4);
        rsA4[h] = 1.0f / suA[0];
        rsB4[h] = 1.0f / suB[0];
    }

    // ---- V tiles (stream 16..23), NORMAL orientation: D-frag == PV A-op ----
    #pragma unroll
    for (int c = 0; c < 8; ++c) {
        int t = 16 + c;
        PIPE_WAIT(1);
        const u16* slot = ring + (t % 3) * 2048;
        float bvA = qkvbL[(16 + c) * 16 + q16];     // bias on col = d = q16
        f32x4 accA = {bvA, bvA, bvA, bvA}, accB = accA;
        #pragma unroll
        for (int ks = 0; ks < 4; ++ks) {
            bf16x8 frag = *(const bf16x8*)(slot + ks * 512 + lane * 8);
            // normal orientation: A = x-frag, B = weight-frag
            accA = __builtin_amdgcn_mfma_f32_16x16x32_bf16(axA[ks].v, frag, accA, 0, 0, 0);
            accB = __builtin_amdgcn_mfma_f32_16x16x32_bf16(axB[ks].v, frag, accB, 0, 0, 0);
        }
        // lane holds V[tok=4g+r][d=q16] -> pack along tok: PV A-operand.
        F4 vpA; vpA.u[0] = pkbf(accA[0], accA[1]); vpA.u[1] = pkbf(accA[2], accA[3]);
        F4 vpB; vpB.u[0] = pkbf(accB[0], accB[1]); vpB.u[1] = pkbf(accB[2], accB[3]);
        int hh = c >> 1;
        f32x4 oA = mfma16(vpA, pPA[hh], z4);
        f32x4 oB = mfma16(vpB, pPB[hh], z4);
        float ra = rsA4[hh], rb = rsB4[hh];
        OpkA[c][0] = pkbf(oA[0] * ra, oA[1] * ra);
        OpkA[c][1] = pkbf(oA[2] * ra, oA[3] * ra);
        OpkB[c][0] = pkbf(oB[0] * rb, oB[1] * rb);
        OpkB[c][1] = pkbf(oB[2] * rb, oB[3] * rb);
        stage_tile(wfrag, lds, t + 2, wave, lane);
    }

    // ---- proj tiles (24..31): chunk-pair full-K=32; in-pipeline stores ----
    // vmcnt is FIFO: counts below account for the 4 younger stores per phase.
    const long obaseA = ((long)b * 16384 + nTok) * 128;
    const long obaseB = obaseA + 512;
    #pragma unroll
    for (int nt = 0; nt < 8; ++nt) {
        int t = 24 + nt;
        if (nt == 0)      PIPE_WAIT(1)
        else if (nt == 7) PIPE_WAIT(2)
        else              PIPE_WAIT(3)
        const u32* slot32 = (const u32*)(ring + (t % 3) * 2048);
        float4 pb = *(const float4*)&projbL[nt * 16 + 4 * g];
        f32x4 accA = {pb.x, pb.y, pb.z, pb.w}, accB = accA;
        #pragma unroll
        for (int cp = 0; cp < 4; ++cp) {
            int c = 2 * cp;
            u32x2 wa = *(const u32x2*)&slot32[c * 128 + lane * 2];
            u32x2 wb = *(const u32x2*)&slot32[(c + 1) * 128 + lane * 2];
            F8 wf; wf.u[0] = wa.x; wf.u[1] = wa.y; wf.u[2] = wb.x; wf.u[3] = wb.y;
            F8 bA; bA.u[0] = OpkA[c][0]; bA.u[1] = OpkA[c][1];
                   bA.u[2] = OpkA[c+1][0]; bA.u[3] = OpkA[c+1][1];
            F8 bB; bB.u[0] = OpkB[c][0]; bB.u[1] = OpkB[c][1];
                   bB.u[2] = OpkB[c+1][0]; bB.u[3] = OpkB[c+1][1];
            accA = __builtin_amdgcn_mfma_f32_16x16x32_bf16(wf.v, bA.v, accA, 0, 0, 0);
            accB = __builtin_amdgcn_mfma_f32_16x16x32_bf16(wf.v, bB.v, accB, 0, 0, 0);
        }
        float4 oA; oA.x = accA[0]; oA.y = accA[1]; oA.z = accA[2]; oA.w = accA[3];
        *(float4*)&out[obaseA + nt * 16 + 4 * g] = oA;
        float4 oB; oB.x = accB[0]; oB.y = accB[1]; oB.z = accB[2]; oB.w = accB[3];
        *(float4*)&out[obaseB + nt * 16 + 4 * g] = oB;
        if (nt < 6) stage_tile(wfrag, lds, t + 2, wave, lane);
    }
}

extern "C" void kernel_launch(void* const* d_in, const int* in_sizes, int n_in,
                              void* d_out, int out_size, void* d_ws, size_t ws_size,
                              hipStream_t stream)
{
    const float* x        = (const float*)d_in[0];
    const float* qkv_w    = (const float*)d_in[3];
    const float* qkv_b    = (const float*)d_in[4];
    const float* proj_w   = (const float*)d_in[5];
    const float* proj_b   = (const float*)d_in[6];
    const float* bias_tbl = (const float*)d_in[7];

    u16*   wsb = (u16*)d_ws;
    float* wsf = (float*)d_ws;

    prep_kernel<<<230, 256, 0, stream>>>(qkv_w, proj_w, bias_tbl, qkv_b, wsb, wsf);
    winattn_kernel<<<2048, 256, 0, stream>>>(x, wsb, proj_b, (float*)d_out);
}

// Round 21
// 71.884 us; speedup vs baseline: 2.4315x; 1.0091x over previous
//
#include <hip/hip_runtime.h>

typedef unsigned short u16;
typedef unsigned int   u32;
typedef __attribute__((ext_vector_type(8))) short bf16x8;   // 8 bf16 = 4 VGPRs
typedef __attribute__((ext_vector_type(4))) short bf16x4;   // 4 bf16 = 2 VGPRs
typedef __attribute__((ext_vector_type(4))) float f32x4;    // MFMA 16x16 accumulator
typedef __attribute__((ext_vector_type(2))) u32 u32x2;

union F8 { bf16x8 v; u32 u[4]; };
union F4 { bf16x4 v; u32 u[2]; };

__device__ __forceinline__ u16 f2b(float f) {
    unsigned u = __builtin_bit_cast(unsigned, f);
    return (u16)((u + 0x7FFFu + ((u >> 16) & 1u)) >> 16);   // RNE fp32->bf16
}
// HOT-PATH pack: round-half-UP (u+0x8000) + v_perm_b32 = 3 VALU (vs 7 for
// full RNE). Differs from RNE only on exact 1-ulp ties (~2^-16/value) —
// absmax margin is 5x, safe. Prep keeps exact RNE.
// (gfx950 lessons: asm v_cvt_pk_bf16_f32 rounds toward ZERO -> 2.25e-2 error
// (R10); _1k MFMA builtins NaN (R6/7); tight launch_bounds min-waves ->
// spill catastrophe (R17); setprio null (R18); UNPINNED s_barrier lets the
// scheduler hoist ds_reads across the cross-wave DMA rendezvous -> replay
// races (R19: pin BOTH sides). Avoid all.)
__device__ __forceinline__ u32 pkbf(float a, float b) {
#if __has_builtin(__builtin_amdgcn_perm)
    u32 ua = __builtin_bit_cast(u32, a) + 0x8000u;
    u32 ub = __builtin_bit_cast(u32, b) + 0x8000u;
    return __builtin_amdgcn_perm(ub, ua, 0x07060302u);  // {ub.hi16, ua.hi16}
#else
    return ((u32)f2b(b) << 16) | (u32)f2b(a);
#endif
}

// K=16 MFMA via the proven K=32 instruction: data in k-slots 0-3, zeros in
// 4-7, identically on both operands -> exact.
__device__ __forceinline__ f32x4 mfma16(F4 a, F4 b, f32x4 c) {
    F8 a8, b8;
    a8.u[0] = a.u[0]; a8.u[1] = a.u[1]; a8.u[2] = 0; a8.u[3] = 0;
    b8.u[0] = b.u[0]; b8.u[1] = b.u[1]; b8.u[2] = 0; b8.u[3] = 0;
    return __builtin_amdgcn_mfma_f32_16x16x32_bf16(a8.v, b8.v, c, 0, 0, 0);
}

// Stage one 1KB fragment (this wave's quarter of stream tile t) into the LDS
// ring, zero VGPR cost. Stream tile t at byte t*4096; ring slot = t%3.
__device__ __forceinline__ void stage_tile(const u16* wfrag, u16* ldsbase,
                                           int t, int wave, int lane) {
    const char* gp = (const char*)wfrag + (((t * 4 + wave) << 10) | (lane << 4));
    char* lp = (char*)ldsbase + (((t % 3) << 12) | (wave << 10));
    __builtin_amdgcn_global_load_lds(
        (const __attribute__((address_space(1))) void*)gp,
        (__attribute__((address_space(3))) void*)lp, 16, 0, 0);
}

// Counted-vmcnt pipeline wait + raw barrier, DOUBLE-pinned: waves read tiles
// staged partly by OTHER waves, so no ds_read may cross the s_barrier in
// either direction (LLVM's s_barrier intrinsic does not model memory).
#define PIPE_WAIT(N) { asm volatile("s_waitcnt vmcnt(" #N ")" ::: "memory"); \
    __builtin_amdgcn_sched_barrier(0); __builtin_amdgcn_s_barrier(); \
    __builtin_amdgcn_sched_barrier(0); }

// ---------------------------------------------------------------------------
// Prep: 32-tile fragment STREAM (tile = 4KB), consumption order:
//  tiles 0-15: per head h: Q(2h), Q(2h+1), K(8+2h), K(9+2h)
//              (Q pre-scaled by scale*log2e for exp2-softmax)
//  tiles 16-23: V (qkv nt = tile index), K=32 B-frags
//  tiles 24-31: proj nt 0-7, K=16 u32 frags (c=0..7 per tile)
//  float 32768..33791: bias dense [h][query][key] * log2e
//  float 33792..34175: qkv_b (Q part * scale*log2e).
// ---------------------------------------------------------------------------
__global__ void prep_kernel(const float* __restrict__ qkv_w,
                            const float* __restrict__ proj_w,
                            const float* __restrict__ bias_tbl,
                            const float* __restrict__ qkv_b,
                            u16* __restrict__ wsb, float* __restrict__ wsf)
{
    const float l2e    = 1.4426950408889634f;            // log2(e)
    const float scale2 = 0.17677669529663689f * l2e;     // 32^-0.5 * log2e
    int tid = blockIdx.x * 256 + threadIdx.x;
    if (tid < 49152) {                      // qkv stream tiles 0..23
        int i = tid & 7, l = (tid >> 3) & 63, w = (tid >> 9) & 3, t = tid >> 11;
        int nt;
        if (t < 16) { int h = t >> 2, r = t & 3;
                      nt = (r < 2) ? (2 * h + r) : (8 + 2 * h + (r - 2)); }
        else nt = t;                        // V tiles: nt = 16..23
        int k = w * 32 + (l >> 4) * 8 + i;
        int col = nt * 16 + (l & 15);
        float wv = qkv_w[k * 384 + col];
        if (col < 128) wv *= scale2;        // fold scale AND log2e into Q
        wsb[tid] = f2b(wv);
    } else if (tid < 57344) {               // proj stream tiles 24..31
        int e = tid - 49152;
        int nt = e >> 10, rem = e & 1023;
        int c = rem >> 7, le = rem & 127, l = le >> 1, j = le & 1;
        int col = nt * 16 + (l & 15);
        int d = c * 16 + 4 * (l >> 4) + 2 * j;
        u32 val = ((u32)f2b(proj_w[(d + 1) * 128 + col]) << 16)
                |  (u32)f2b(proj_w[d * 128 + col]);
        ((u32*)wsb)[(24 + nt) * 1024 + c * 128 + l * 2 + j] = val;
    } else if (tid < 58368) {               // bias expand [h][query][key]*log2e
        int e = tid - 57344;
        int h = e >> 8, t1 = (e >> 4) & 15, t2 = e & 15;
        int idx = ((t1 >> 2) - (t2 >> 2) + 3) * 7 + ((t1 & 3) - (t2 & 3) + 3);
        wsf[32768 + e] = bias_tbl[idx * 4 + h] * l2e;
    } else if (tid < 58752) {               // qkv_b, Q part pre-scaled
        int e = tid - 58368;
        wsf[33792 + e] = qkv_b[e] * (e < 128 ? scale2 : 1.0f);
    }
}

// ---------------------------------------------------------------------------
// Fused window attention (R16/R20 structure = validated optimum):
// 4 waves/block, TWO windows/wave. 3-slot ring, 1 tile/phase, vmcnt(1).
// Transposed qkv D-frags as direct K=16/K=32 MFMA operands; NORMAL-orientation
// V (D-frag == PV A-op, no LDS transpose); ones-MFMA softmax denominator
// (P = exp2 of pre-folded args, no max-sub); K=16-frag proj.
// ---------------------------------------------------------------------------
__global__ __launch_bounds__(256, 4) void winattn_kernel(
    const float* __restrict__ x, const u16* __restrict__ wfrag,
    const float* __restrict__ proj_b, float* __restrict__ out)
{
    __shared__ alignas(16) u16 lds[9216];
    u16* ring = lds;                               // [0, 6144): 3 x 4KB slots
    float* qkvbL  = (float*)(lds + 6144);          // 384 f
    float* biasL  = (float*)(lds + 6912);          // 1024 f
    float* projbL = (float*)(lds + 8960);          // 128 f

    const int tid  = threadIdx.x;
    const int wave = tid >> 6, lane = tid & 63;
    const int g = lane >> 4, q16 = lane & 15;

    const float* wsf = (const float*)wfrag;
    for (int e = tid; e < 384;  e += 256) qkvbL[e] = wsf[33792 + e];
    for (int e = tid; e < 1024; e += 256) biasL[e] = wsf[32768 + e];
    if (tid < 128) projbL[tid] = proj_b[tid];

    const int wpair = blockIdx.x * 4 + wave;
    const int wid0  = wpair * 2;                   // window A; B = wid0+1
    const int b = wid0 >> 10, rem = wid0 & 1023, wi = rem >> 5, wj = rem & 31;
    const int nTok = (wi * 4 + (q16 >> 2)) * 128 + wj * 4 + (q16 & 3);
    const float* xrowA = x + ((long)b * 16384 + nTok) * 128;
    const float* xrowB = xrowA + 512;

    // x fragments (per-lane bytes serve as BOTH A- and B-operand)
    F8 axA[4], axB[4];
    #pragma unroll
    for (int ks = 0; ks < 4; ++ks) {
        const float4* pA = (const float4*)(xrowA + ks * 32 + g * 8);
        float4 a0 = pA[0], a1 = pA[1];
        axA[ks].u[0] = pkbf(a0.x, a0.y); axA[ks].u[1] = pkbf(a0.z, a0.w);
        axA[ks].u[2] = pkbf(a1.x, a1.y); axA[ks].u[3] = pkbf(a1.z, a1.w);
        const float4* pB = (const float4*)(xrowB + ks * 32 + g * 8);
        float4 b0 = pB[0], b1 = pB[1];
        axB[ks].u[0] = pkbf(b0.x, b0.y); axB[ks].u[1] = pkbf(b0.z, b0.w);
        axB[ks].u[2] = pkbf(b1.x, b1.y); axB[ks].u[3] = pkbf(b1.z, b1.w);
    }
    __builtin_amdgcn_sched_barrier(0);  // pin x-loads before the drain
    __syncthreads();                    // tables visible; vmcnt drained to 0

    stage_tile(wfrag, lds, 0, wave, lane);
    stage_tile(wfrag, lds, 1, wave, lane);

    f32x4 z4 = {0.f, 0.f, 0.f, 0.f};
    F4 ones; ones.u[0] = 0x3f803f80u; ones.u[1] = 0x3f803f80u;
    F4 pPA[4], pPB[4];
    float rsA4[4], rsB4[4];
    u32 OpkA[8][2], OpkB[8][2];

    // Consume one qkv tile TRANSPOSED (8 MFMAs), return packed D-frags.
    #define QKV_TILE(T, NT, P0A, P1A, P0B, P1B) {                              \
        const u16* slot = ring + ((T) % 3) * 2048;                             \
        float4 bb = *(const float4*)&qkvbL[(NT) * 16 + 4 * g];                 \
        f32x4 accA = {bb.x, bb.y, bb.z, bb.w}, accB = accA;                    \
        _Pragma("unroll")                                                      \
        for (int ks = 0; ks < 4; ++ks) {                                       \
            bf16x8 frag = *(const bf16x8*)(slot + ks * 512 + lane * 8);        \
            accA = __builtin_amdgcn_mfma_f32_16x16x32_bf16(frag, axA[ks].v, accA, 0, 0, 0); \
            accB = __builtin_amdgcn_mfma_f32_16x16x32_bf16(frag, axB[ks].v, accB, 0, 0, 0); \
        }                                                                      \
        P0A = pkbf(accA[0], accA[1]); P1A = pkbf(accA[2], accA[3]);            \
        P0B = pkbf(accB[0], accB[1]); P1B = pkbf(accB[2], accB[3]);            \
    }

    // ---- per-head Q,K tiles (stream 0..15) + attention ----
    #pragma unroll
    for (int h = 0; h < 4; ++h) {
        u32 QA[2][2], QB[2][2], KA[2][2], KB[2][2];
        #pragma unroll
        for (int r = 0; r < 4; ++r) {
            int t = 4 * h + r;
            PIPE_WAIT(1);
            int nt = (r < 2) ? (2 * h + r) : (8 + 2 * h + (r - 2));
            if (r == 0)      QKV_TILE(t, nt, QA[0][0], QA[0][1], QB[0][0], QB[0][1])
            else if (r == 1) QKV_TILE(t, nt, QA[1][0], QA[1][1], QB[1][0], QB[1][1])
            else if (r == 2) QKV_TILE(t, nt, KA[0][0], KA[0][1], KB[0][0], KB[0][1])
            else             QKV_TILE(t, nt, KA[1][0], KA[1][1], KB[1][0], KB[1][1])
            stage_tile(wfrag, lds, t + 2, wave, lane);
        }
        // QK^T: ONE full K=32 MFMA per window (slot map identical on A and B)
        F8 kfA, qfA, kfB, qfB;
        kfA.u[0]=KA[0][0]; kfA.u[1]=KA[0][1]; kfA.u[2]=KA[1][0]; kfA.u[3]=KA[1][1];
        qfA.u[0]=QA[0][0]; qfA.u[1]=QA[0][1]; qfA.u[2]=QA[1][0]; qfA.u[3]=QA[1][1];
        kfB.u[0]=KB[0][0]; kfB.u[1]=KB[0][1]; kfB.u[2]=KB[1][0]; kfB.u[3]=KB[1][1];
        qfB.u[0]=QB[0][0]; qfB.u[1]=QB[0][1]; qfB.u[2]=QB[1][0]; qfB.u[3]=QB[1][1];
        f32x4 sA = __builtin_amdgcn_mfma_f32_16x16x32_bf16(kfA.v, qfA.v, z4, 0, 0, 0);
        f32x4 sB = __builtin_amdgcn_mfma_f32_16x16x32_bf16(kfB.v, qfB.v, z4, 0, 0, 0);
        // softmax: P = exp2(S + bias')  (scale & log2e pre-folded; no max-sub)
        float4 bias4 = *(const float4*)&biasL[(h * 16 + q16) * 16 + 4 * g];
        float eA0 = exp2f(sA[0] + bias4.x), eA1 = exp2f(sA[1] + bias4.y);
        float eA2 = exp2f(sA[2] + bias4.z), eA3 = exp2f(sA[3] + bias4.w);
        float eB0 = exp2f(sB[0] + bias4.x), eB1 = exp2f(sB[1] + bias4.y);
        float eB2 = exp2f(sB[2] + bias4.z), eB3 = exp2f(sB[3] + bias4.w);
        pPA[h].u[0] = pkbf(eA0, eA1); pPA[h].u[1] = pkbf(eA2, eA3);
        pPB[h].u[0] = pkbf(eB0, eB1); pPB[h].u[1] = pkbf(eB2, eB3);
        f32x4 suA = mfma16(ones, pPA[h], z4);
        f32x4 suB = mfma16(ones, pPB[h], z4);
        rsA4[h] = 1.0f / suA[0];
        rsB4[h] = 1.0f / suB[0];
    }

    // ---- V tiles (stream 16..23), NORMAL orientation: D-frag == PV A-op ----
    #pragma unroll
    for (int c = 0; c < 8; ++c) {
        int t = 16 + c;
        PIPE_WAIT(1);
        const u16* slot = ring + (t % 3) * 2048;
        float bvA = qkvbL[(16 + c) * 16 + q16];     // bias on col = d = q16
        f32x4 accA = {bvA, bvA, bvA, bvA}, accB = accA;
        #pragma unroll
        for (int ks = 0; ks < 4; ++ks) {
            bf16x8 frag = *(const bf16x8*)(slot + ks * 512 + lane * 8);
            // normal orientation: A = x-frag, B = weight-frag
            accA = __builtin_amdgcn_mfma_f32_16x16x32_bf16(axA[ks].v, frag, accA, 0, 0, 0);
            accB = __builtin_amdgcn_mfma_f32_16x16x32_bf16(axB[ks].v, frag, accB, 0, 0, 0);
        }
        // lane holds V[tok=4g+r][d=q16] -> pack along tok: PV A-operand.
        F4 vpA; vpA.u[0] = pkbf(accA[0], accA[1]); vpA.u[1] = pkbf(accA[2], accA[3]);
        F4 vpB; vpB.u[0] = pkbf(accB[0], accB[1]); vpB.u[1] = pkbf(accB[2], accB[3]);
        int hh = c >> 1;
        f32x4 oA = mfma16(vpA, pPA[hh], z4);
        f32x4 oB = mfma16(vpB, pPB[hh], z4);
        float ra = rsA4[hh], rb = rsB4[hh];
        OpkA[c][0] = pkbf(oA[0] * ra, oA[1] * ra);
        OpkA[c][1] = pkbf(oA[2] * ra, oA[3] * ra);
        OpkB[c][0] = pkbf(oB[0] * rb, oB[1] * rb);
        OpkB[c][1] = pkbf(oB[2] * rb, oB[3] * rb);
        stage_tile(wfrag, lds, t + 2, wave, lane);
    }

    // ---- proj tiles (24..31): chunk-pair full-K=32; in-pipeline stores ----
    // vmcnt is FIFO: counts below account for the 4 younger stores per phase.
    const long obaseA = ((long)b * 16384 + nTok) * 128;
    const long obaseB = obaseA + 512;
    #pragma unroll
    for (int nt = 0; nt < 8; ++nt) {
        int t = 24 + nt;
        if (nt == 0)      PIPE_WAIT(1)
        else if (nt == 7) PIPE_WAIT(2)
        else              PIPE_WAIT(3)
        const u32* slot32 = (const u32*)(ring + (t % 3) * 2048);
        float4 pb = *(const float4*)&projbL[nt * 16 + 4 * g];
        f32x4 accA = {pb.x, pb.y, pb.z, pb.w}, accB = accA;
        #pragma unroll
        for (int cp = 0; cp < 4; ++cp) {
            int c = 2 * cp;
            u32x2 wa = *(const u32x2*)&slot32[c * 128 + lane * 2];
            u32x2 wb = *(const u32x2*)&slot32[(c + 1) * 128 + lane * 2];
            F8 wf; wf.u[0] = wa.x; wf.u[1] = wa.y; wf.u[2] = wb.x; wf.u[3] = wb.y;
            F8 bA; bA.u[0] = OpkA[c][0]; bA.u[1] = OpkA[c][1];
                   bA.u[2] = OpkA[c+1][0]; bA.u[3] = OpkA[c+1][1];
            F8 bB; bB.u[0] = OpkB[c][0]; bB.u[1] = OpkB[c][1];
                   bB.u[2] = OpkB[c+1][0]; bB.u[3] = OpkB[c+1][1];
            accA = __builtin_amdgcn_mfma_f32_16x16x32_bf16(wf.v, bA.v, accA, 0, 0, 0);
            accB = __builtin_amdgcn_mfma_f32_16x16x32_bf16(wf.v, bB.v, accB, 0, 0, 0);
        }
        float4 oA; oA.x = accA[0]; oA.y = accA[1]; oA.z = accA[2]; oA.w = accA[3];
        *(float4*)&out[obaseA + nt * 16 + 4 * g] = oA;
        float4 oB; oB.x = accB[0]; oB.y = accB[1]; oB.z = accB[2]; oB.w = accB[3];
        *(float4*)&out[obaseB + nt * 16 + 4 * g] = oB;
        if (nt < 6) stage_tile(wfrag, lds, t + 2, wave, lane);
    }
}

extern "C" void kernel_launch(void* const* d_in, const int* in_sizes, int n_in,
                              void* d_out, int out_size, void* d_ws, size_t ws_size,
                              hipStream_t stream)
{
    const float* x        = (const float*)d_in[0];
    const float* qkv_w    = (const float*)d_in[3];
    const float* qkv_b    = (const float*)d_in[4];
    const float* proj_w   = (const float*)d_in[5];
    const float* proj_b   = (const float*)d_in[6];
    const float* bias_tbl = (const float*)d_in[7];

    u16*   wsb = (u16*)d_ws;
    float* wsf = (float*)d_ws;

    prep_kernel<<<230, 256, 0, stream>>>(qkv_w, proj_w, bias_tbl, qkv_b, wsb, wsf);
    winattn_kernel<<<2048, 256, 0, stream>>>(x, wsb, proj_b, (float*)d_out);
}